// Round 1
// 898.767 us; speedup vs baseline: 1.1473x; 1.1473x over previous
//
#include <hip/hip_runtime.h>
#include <cstdint>
#include <cstddef>

typedef __bf16 bf16;
typedef __attribute__((ext_vector_type(8))) __bf16 bf16x8;
typedef __attribute__((ext_vector_type(4))) __bf16 bf16x4;
typedef __attribute__((ext_vector_type(4))) float f32x4;

#define DM 1024
#define NH 16
#define DEPTH 64
#define SEQ 2048
#define NB 2

__device__ __forceinline__ void split2(float x, bf16& h, bf16& l) {
    h = (bf16)x;
    l = (bf16)(x - (float)h);
}

__device__ __forceinline__ f32x4 mfma16(bf16x8 a, bf16x8 b, f32x4 c) {
    return __builtin_amdgcn_mfma_f32_16x16x32_bf16(a, b, c, 0, 0, 0);
}

// async global->LDS, 16B per lane; LDS dest is wave-uniform base + lane*16
__device__ __forceinline__ void gload16(const bf16* g, bf16* s) {
    __builtin_amdgcn_global_load_lds(
        (const __attribute__((address_space(1))) void*)g,
        (__attribute__((address_space(3))) void*)s, 16, 0, 0);
}

// ---------------- elementwise split: fp32 -> bf16 hi/lo ----------------
__global__ __launch_bounds__(256) void split_kernel(const float* __restrict__ x,
                                                    bf16* __restrict__ hi,
                                                    bf16* __restrict__ lo, int n) {
    int i = (blockIdx.x * 256 + threadIdx.x) * 4;
    if (i >= n) return;
    float4 v = *(const float4*)(x + i);
    bf16 h0, l0, h1, l1, h2, l2, h3, l3;
    split2(v.x, h0, l0); split2(v.y, h1, l1);
    split2(v.z, h2, l2); split2(v.w, h3, l3);
    bf16x4 hv = {h0, h1, h2, h3}, lv = {l0, l1, l2, l3};
    *(bf16x4*)(hi + i) = hv;
    *(bf16x4*)(lo + i) = lv;
}

// ---------------- weight transpose+split: w[k][n] -> wT hi/lo [n][k] ----------------
__global__ __launch_bounds__(256) void wsplit_t(const float* __restrict__ w,
                                                bf16* __restrict__ hi,
                                                bf16* __restrict__ lo) {
    __shared__ float tile[64][65];
    int t = threadIdx.x;
    int c0 = blockIdx.x * 64;  // n
    int r0 = blockIdx.y * 64;  // k
    int r = t >> 2, cg = (t & 3) * 16;
#pragma unroll
    for (int j = 0; j < 16; j += 4) {
        float4 v = *(const float4*)(w + (size_t)(r0 + r) * DM + c0 + cg + j);
        tile[r][cg + j] = v.x; tile[r][cg + j + 1] = v.y;
        tile[r][cg + j + 2] = v.z; tile[r][cg + j + 3] = v.w;
    }
    __syncthreads();
    int n = t >> 2, kg = (t & 3) * 16;
    bf16x8 hv0, hv1, lv0, lv1;
#pragma unroll
    for (int i = 0; i < 8; i++) {
        bf16 h, l;
        split2(tile[kg + i][n], h, l); hv0[i] = h; lv0[i] = l;
        split2(tile[kg + 8 + i][n], h, l); hv1[i] = h; lv1[i] = l;
    }
    size_t o = (size_t)(c0 + n) * DM + r0 + kg;
    *(bf16x8*)(hi + o) = hv0; *(bf16x8*)(hi + o + 8) = hv1;
    *(bf16x8*)(lo + o) = lv0; *(bf16x8*)(lo + o + 8) = lv1;
}

// ---------------- split-precision GEMM: C[M,1024] = A @ W (+bias) ----------------
// A as hi/lo [M][1024]; W transposed+split Bt hi/lo [1024][1024] (Bt[n][k]=W[k][n]).
// Cf != null: write fp32 (+bias). Else write bf16 hi/lo (+bias).
// 512 thr / 8 waves; 128x128 tile, BK=64; double-buffered global_load_lds staging
// with XOR-swizzled source (linear LDS dest, swizzled ds_read -> conflict-free).
__global__ __launch_bounds__(512) void gemm_split(
    const bf16* __restrict__ Ah, const bf16* __restrict__ Al,
    const bf16* __restrict__ Bh, const bf16* __restrict__ Bl,
    const float* __restrict__ bias,
    bf16* __restrict__ Ch, bf16* __restrict__ Cl, float* __restrict__ Cf) {
    __shared__ bf16 lds4[2][4][128 * 64];  // [dbuf][Ah,Al,Bh,Bl][row*64+e] = 128 KiB
    int t = threadIdx.x;
    int m0 = blockIdx.x * 128, n0 = blockIdx.y * 128;
    int l = t & 63, w = t >> 6;
    int quad = l >> 4, ln = l & 15;
    int wr = w >> 2, wc = w & 3;  // wave tile: rows wr*64 (M), cols wc*32 (N)
    int rch = l >> 3, c16 = l & 7;
    int sx0 = (quad ^ (ln & 7)) << 3;  // swizzled phys slot (elements), k2 flips bit5

    // staging role: buffer = w>>1 (0:Ah 1:Al 2:Bh 3:Bl), 8 of 16 chunks each
    int bufid = w >> 1;
    const bf16* src = (bufid == 0) ? Ah : (bufid == 1) ? Al : (bufid == 2) ? Bh : Bl;
    int rbase = (bufid < 2) ? m0 : n0;
    int ch0 = (w & 1) * 8;

    auto stage = [&](int db, int k0) {
#pragma unroll
        for (int j = 0; j < 8; j++) {
            int chunk = ch0 + j;
            int row = chunk * 8 + rch;
            gload16(src + (size_t)(rbase + row) * DM + k0 + ((c16 ^ (row & 7)) << 3),
                    &lds4[db][bufid][chunk * 512]);
        }
    };

    f32x4 acc[4][2];
#pragma unroll
    for (int r = 0; r < 4; r++)
#pragma unroll
        for (int c = 0; c < 2; c++) acc[r][c] = (f32x4){0.f, 0.f, 0.f, 0.f};

    stage(0, 0);
    __syncthreads();

    for (int kk = 0; kk < DM / 64; kk++) {
        int cur = kk & 1;
        if (kk < DM / 64 - 1) stage(cur ^ 1, (kk + 1) * 64);  // issue-early prefetch
#pragma unroll
        for (int k2 = 0; k2 < 2; k2++) {
            int so = sx0 ^ (k2 << 5);
            bf16x8 ah[4], al[4], bh[2], bl[2];
#pragma unroll
            for (int r = 0; r < 4; r++) {
                int ro = (wr * 64 + r * 16 + ln) << 6;
                ah[r] = *(const bf16x8*)&lds4[cur][0][ro + so];
                al[r] = *(const bf16x8*)&lds4[cur][1][ro + so];
            }
#pragma unroll
            for (int c = 0; c < 2; c++) {
                int ro = (wc * 32 + c * 16 + ln) << 6;
                bh[c] = *(const bf16x8*)&lds4[cur][2][ro + so];
                bl[c] = *(const bf16x8*)&lds4[cur][3][ro + so];
            }
#pragma unroll
            for (int r = 0; r < 4; r++)
#pragma unroll
                for (int c = 0; c < 2; c++) {
                    acc[r][c] = mfma16(ah[r], bh[c], acc[r][c]);
                    acc[r][c] = mfma16(ah[r], bl[c], acc[r][c]);
                    acc[r][c] = mfma16(al[r], bh[c], acc[r][c]);
                }
        }
        __syncthreads();  // drains vmcnt(0): prefetched tile complete; LDS safe to reuse
    }

#pragma unroll
    for (int c = 0; c < 2; c++) {
        int col = n0 + wc * 32 + c * 16 + ln;
        float bv = bias[col];
#pragma unroll
        for (int r = 0; r < 4; r++) {
            int rowb = m0 + wr * 64 + r * 16 + quad * 4;
#pragma unroll
            for (int i = 0; i < 4; i++) {
                float v = acc[r][c][i] + bv;
                size_t o = (size_t)(rowb + i) * DM + col;
                if (Cf) {
                    Cf[o] = v;
                } else {
                    bf16 h, lo_;
                    split2(v, h, lo_);
                    Ch[o] = h; Cl[o] = lo_;
                }
            }
        }
    }
}

// ---------------- per-head V transpose: vh [B,S,D] -> vt [B,H,64,2048] ----------------
__global__ __launch_bounds__(256) void vtrans(const bf16* __restrict__ vh_h,
                                              const bf16* __restrict__ vh_l,
                                              bf16* __restrict__ vt_h,
                                              bf16* __restrict__ vt_l) {
    __shared__ bf16 tile[64][72];
    int t = threadIdx.x;
    int s0 = blockIdx.x * 64;
    int bh = blockIdx.y;
    int b = bh >> 4, h = bh & 15;
    const bf16* src[2] = {vh_h, vh_l};
    bf16* dst[2] = {vt_h, vt_l};
#pragma unroll
    for (int p = 0; p < 2; p++) {
#pragma unroll
        for (int rnd = 0; rnd < 2; rnd++) {
            int unit = t + rnd * 256;
            int r = unit >> 3, cg = (unit & 7) * 8;
            *(bf16x8*)&tile[r][cg] =
                *(const bf16x8*)(src[p] + (size_t)(b * SEQ + s0 + r) * DM + h * DEPTH + cg);
        }
        __syncthreads();
#pragma unroll
        for (int rnd = 0; rnd < 2; rnd++) {
            int unit = t + rnd * 256;
            int d = unit >> 3, sg = (unit & 7) * 8;
            bf16x8 v;
#pragma unroll
            for (int j = 0; j < 8; j++) v[j] = tile[sg + j][d];
            *(bf16x8*)(dst[p] + (size_t)(bh * DEPTH + d) * SEQ + s0 + sg) = v;
        }
        __syncthreads();
    }
}

// ---------------- fused attention: softmax(QK^T/8 + mask) -> attn out + ctx ----------------
// 512 thr / 8 waves; Q-tile = 128 rows (wave w owns rows w*16..w*16+15).
// K/V staged via double-buffered global_load_lds with swizzled source; P is wave-private
// (no mid-tile barrier); attn stored nontemporal.
#define PST 76  // P LDS stride (conflict-free for both write and b128 read patterns)
__global__ __launch_bounds__(512) void attn_kernel(
    const bf16* __restrict__ qh_h, const bf16* __restrict__ qh_l,
    const bf16* __restrict__ kh_h, const bf16* __restrict__ kh_l,
    const bf16* __restrict__ vt_h, const bf16* __restrict__ vt_l,
    const float* __restrict__ mask,
    float* __restrict__ attn, bf16* __restrict__ ctx_h, bf16* __restrict__ ctx_l) {
    __shared__ bf16 lK[2][2][64 * 64];  // [dbuf][h/l] 32 KiB
    __shared__ bf16 lV[2][2][64 * 64];  // 32 KiB
    __shared__ bf16 lPh[128 * PST], lPl[128 * PST];
    int t = threadIdx.x;
    int m0 = blockIdx.x * 128;
    int bh = blockIdx.y;
    int b = bh >> 4, h = bh & 15;
    int l = t & 63, w = t >> 6, quad = l >> 4, ln = l & 15;
    int rch = l >> 3, c16 = l & 7;
    int sx0 = (quad ^ (ln & 7)) << 3;

    // Q fragments straight from global (coalesced 64B per 4-lane group; once per block)
    bf16x8 qf_h[2], qf_l[2];
    {
        size_t qrow = (size_t)(b * SEQ + m0 + w * 16 + ln) * DM + h * DEPTH;
#pragma unroll
        for (int kk = 0; kk < 2; kk++) {
            qf_h[kk] = *(const bf16x8*)(qh_h + qrow + kk * 32 + quad * 8);
            qf_l[kk] = *(const bf16x8*)(qh_l + qrow + kk * 32 + quad * 8);
        }
    }

    // pass-1 staging: waves 0-3 -> K hi, waves 4-7 -> K lo; 2 chunks each
    const bf16* ksrc1 = (w < 4) ? kh_h : kh_l;
    int kbuf1 = (w < 4) ? 0 : 1;
    int kch0 = (w & 3) * 2;
    auto stageK = [&](int db, int t0) {
#pragma unroll
        for (int j = 0; j < 2; j++) {
            int chunk = kch0 + j;
            int row = chunk * 8 + rch;
            gload16(ksrc1 + (size_t)(b * SEQ + t0 + row) * DM + h * DEPTH +
                        ((c16 ^ (row & 7)) << 3),
                    &lK[db][kbuf1][chunk * 512]);
        }
    };
    // pass-2 staging: wave w -> target w>>1 (0:Kh 1:Kl 2:Vh 3:Vl); 4 chunks each
    int tgt = w >> 1;
    const bf16* ksrc2 = (tgt == 0) ? kh_h : (tgt == 1) ? kh_l : (tgt == 2) ? vt_h : vt_l;
    auto stageKV = [&](int db, int t0) {
        bf16* dst = (tgt == 0) ? &lK[db][0][0] : (tgt == 1) ? &lK[db][1][0]
                  : (tgt == 2) ? &lV[db][0][0] : &lV[db][1][0];
#pragma unroll
        for (int j = 0; j < 4; j++) {
            int chunk = (w & 1) * 4 + j;
            int row = chunk * 8 + rch;
            size_t off = (tgt >= 2)
                             ? ((size_t)(bh * DEPTH + row) * SEQ + t0)
                             : ((size_t)(b * SEQ + t0 + row) * DM + h * DEPTH);
            gload16(ksrc2 + off + ((c16 ^ (row & 7)) << 3), dst + chunk * 512);
        }
    };

    // ---- pass 1: row sums of exp(logit) ----
    float rowsum[4] = {0.f, 0.f, 0.f, 0.f};
    stageK(0, 0);
    __syncthreads();
    for (int ct = 0; ct < SEQ / 64; ct++) {
        int db = ct & 1;
        if (ct < SEQ / 64 - 1) stageK(db ^ 1, (ct + 1) * 64);
        int t0 = ct * 64;
#pragma unroll
        for (int c = 0; c < 4; c++) {
            f32x4 s = (f32x4){0.f, 0.f, 0.f, 0.f};
#pragma unroll
            for (int kk = 0; kk < 2; kk++) {
                int so = sx0 ^ (kk << 5);
                int ro = (c * 16 + ln) << 6;
                bf16x8 kb_h = *(const bf16x8*)&lK[db][0][ro + so];
                bf16x8 kb_l = *(const bf16x8*)&lK[db][1][ro + so];
                s = mfma16(qf_h[kk], kb_h, s);
                s = mfma16(qf_h[kk], kb_l, s);
                s = mfma16(qf_l[kk], kb_h, s);
            }
            int col = t0 + c * 16 + ln;
            float mv = mask[b * SEQ + col] * -1e9f;
#pragma unroll
            for (int i = 0; i < 4; i++) rowsum[i] += __expf(s[i] * 0.125f + mv);
        }
        __syncthreads();
    }
#pragma unroll
    for (int m = 1; m < 16; m <<= 1)
#pragma unroll
        for (int i = 0; i < 4; i++) rowsum[i] += __shfl_xor(rowsum[i], m, 64);
    float linv[4];
#pragma unroll
    for (int i = 0; i < 4; i++) linv[i] = 1.0f / rowsum[i];

    // ---- pass 2: write attn, accumulate ctx = P @ V ----
    f32x4 o[4];
#pragma unroll
    for (int c2 = 0; c2 < 4; c2++) o[c2] = (f32x4){0.f, 0.f, 0.f, 0.f};

    stageKV(0, 0);
    __syncthreads();
    for (int ct = 0; ct < SEQ / 64; ct++) {
        int db = ct & 1;
        if (ct < SEQ / 64 - 1) stageKV(db ^ 1, (ct + 1) * 64);
        int t0 = ct * 64;
#pragma unroll
        for (int c = 0; c < 4; c++) {
            f32x4 s = (f32x4){0.f, 0.f, 0.f, 0.f};
#pragma unroll
            for (int kk = 0; kk < 2; kk++) {
                int so = sx0 ^ (kk << 5);
                int ro = (c * 16 + ln) << 6;
                bf16x8 kb_h = *(const bf16x8*)&lK[db][0][ro + so];
                bf16x8 kb_l = *(const bf16x8*)&lK[db][1][ro + so];
                s = mfma16(qf_h[kk], kb_h, s);
                s = mfma16(qf_h[kk], kb_l, s);
                s = mfma16(qf_l[kk], kb_h, s);
            }
            int col = t0 + c * 16 + ln;
            float mv = mask[b * SEQ + col] * -1e9f;
#pragma unroll
            for (int i = 0; i < 4; i++) {
                float p = __expf(s[i] * 0.125f + mv) * linv[i];
                __builtin_nontemporal_store(
                    p, attn + ((size_t)bh * SEQ + m0 + w * 16 + quad * 4 + i) * SEQ + col);
                bf16 ph, pl;
                split2(p, ph, pl);
                int pr = (w * 16 + quad * 4 + i) * PST + c * 16 + ln;
                lPh[pr] = ph;
                lPl[pr] = pl;
            }
        }
        // P is wave-private (wave w writes & reads only rows w*16..w*16+15): no barrier
#pragma unroll
        for (int kk = 0; kk < 2; kk++) {
            int so = sx0 ^ (kk << 5);
            bf16x8 pa_h = *(const bf16x8*)&lPh[(w * 16 + ln) * PST + kk * 32 + quad * 8];
            bf16x8 pa_l = *(const bf16x8*)&lPl[(w * 16 + ln) * PST + kk * 32 + quad * 8];
#pragma unroll
            for (int c2 = 0; c2 < 4; c2++) {
                int ro = (c2 * 16 + ln) << 6;
                bf16x8 vb_h = *(const bf16x8*)&lV[db][0][ro + so];
                bf16x8 vb_l = *(const bf16x8*)&lV[db][1][ro + so];
                o[c2] = mfma16(pa_h, vb_h, o[c2]);
                o[c2] = mfma16(pa_h, vb_l, o[c2]);
                o[c2] = mfma16(pa_l, vb_h, o[c2]);
            }
        }
        __syncthreads();
    }

    // epilogue: ctx hi/lo in [B,S,D] layout
#pragma unroll
    for (int c2 = 0; c2 < 4; c2++) {
        int d = c2 * 16 + ln;
#pragma unroll
        for (int i = 0; i < 4; i++) {
            int row = m0 + w * 16 + quad * 4 + i;
            bf16 hh, ll;
            split2(o[c2][i], hh, ll);
            size_t oo = (size_t)(b * SEQ + row) * DM + h * DEPTH + d;
            ctx_h[oo] = hh; ctx_l[oo] = ll;
        }
    }
}

extern "C" void kernel_launch(void* const* d_in, const int* in_sizes, int n_in,
                              void* d_out, int out_size, void* d_ws, size_t ws_size,
                              hipStream_t stream) {
    (void)in_sizes; (void)n_in; (void)out_size; (void)ws_size;
    const float* q    = (const float*)d_in[0];
    const float* k    = (const float*)d_in[1];
    const float* v    = (const float*)d_in[2];
    const float* mask = (const float*)d_in[3];
    const float* wq   = (const float*)d_in[4];
    const float* bq   = (const float*)d_in[5];
    const float* wk   = (const float*)d_in[6];
    const float* bk   = (const float*)d_in[7];
    const float* wv   = (const float*)d_in[8];
    const float* bv   = (const float*)d_in[9];
    const float* wo   = (const float*)d_in[10];
    const float* bo   = (const float*)d_in[11];

    float* out  = (float*)d_out;
    float* attn = out + (size_t)NB * SEQ * DM;

    const size_t E  = (size_t)NB * SEQ * DM;  // 4194304
    const size_t WE = (size_t)DM * DM;        // 1048576

    bf16* p = (bf16*)d_ws;
    bf16* q_h = p;            bf16* q_l = q_h + E;
    bf16* k_h = q_l + E;      bf16* k_l = k_h + E;
    bf16* v_h = k_l + E;      bf16* v_l = v_h + E;
    bf16* wqT_h = v_l + E;    bf16* wqT_l = wqT_h + WE;
    bf16* wkT_h = wqT_l + WE; bf16* wkT_l = wkT_h + WE;
    bf16* wvT_h = wkT_l + WE; bf16* wvT_l = wvT_h + WE;
    bf16* woT_h = wvT_l + WE; bf16* woT_l = woT_h + WE;
    bf16* qh_h = woT_l + WE;  bf16* qh_l = qh_h + E;
    bf16* kh_h = qh_l + E;    bf16* kh_l = kh_h + E;
    bf16* vh_h = kh_l + E;    bf16* vh_l = vh_h + E;
    // aliases (safe by kernel ordering):
    bf16* vt_h = q_h;  bf16* vt_l = q_l;   // vtrans runs after all projections
    bf16* ctx_h = k_h; bf16* ctx_l = k_l;  // attention runs after K projection

    dim3 blk(256);
    split_kernel<<<(int)(E / 1024), blk, 0, stream>>>(q, q_h, q_l, (int)E);
    split_kernel<<<(int)(E / 1024), blk, 0, stream>>>(k, k_h, k_l, (int)E);
    split_kernel<<<(int)(E / 1024), blk, 0, stream>>>(v, v_h, v_l, (int)E);
    wsplit_t<<<dim3(16, 16), blk, 0, stream>>>(wq, wqT_h, wqT_l);
    wsplit_t<<<dim3(16, 16), blk, 0, stream>>>(wk, wkT_h, wkT_l);
    wsplit_t<<<dim3(16, 16), blk, 0, stream>>>(wv, wvT_h, wvT_l);
    wsplit_t<<<dim3(16, 16), blk, 0, stream>>>(wo, woT_h, woT_l);

    gemm_split<<<dim3(32, 8), dim3(512), 0, stream>>>(q_h, q_l, wqT_h, wqT_l, bq, qh_h, qh_l, nullptr);
    gemm_split<<<dim3(32, 8), dim3(512), 0, stream>>>(k_h, k_l, wkT_h, wkT_l, bk, kh_h, kh_l, nullptr);
    gemm_split<<<dim3(32, 8), dim3(512), 0, stream>>>(v_h, v_l, wvT_h, wvT_l, bv, vh_h, vh_l, nullptr);

    vtrans<<<dim3(32, 32), blk, 0, stream>>>(vh_h, vh_l, vt_h, vt_l);

    attn_kernel<<<dim3(16, 32), dim3(512), 0, stream>>>(qh_h, qh_l, kh_h, kh_l, vt_h, vt_l,
                                                        mask, attn, ctx_h, ctx_l);

    gemm_split<<<dim3(32, 8), dim3(512), 0, stream>>>(ctx_h, ctx_l, woT_h, woT_l, bo,
                                                      nullptr, nullptr, out);
}